// Round 15
// baseline (161.961 us; speedup 1.0000x reference)
//
#include <hip/hip_runtime.h>

// LocalEnergy R15: R14 + per-type hoisted A1/B2 weight fragments (loaded once
// per type, reused across both 64-row halves; lazy loads keep only one type's
// B2 live) + __launch_bounds__(256,3) to give the allocator room.
// B=128, L=2048, E=16, H=128. Out = 128 f32.

typedef short bf16x8  __attribute__((ext_vector_type(8)));
typedef float f32x4   __attribute__((ext_vector_type(4)));
typedef float f32x16  __attribute__((ext_vector_type(16)));

constexpr int Lc  = 2048;
constexpr int SHs = 136;   // H1 row stride (shorts) = 272 B

union FragU { uint4 u; bf16x8 v; };

__device__ __forceinline__ unsigned short f2bf(float f) {
    union { float f; unsigned u; } v; v.f = f;
    unsigned u = v.u;
    u = u + 0x7FFFu + ((u >> 16) & 1u);   // RTNE
    return (unsigned short)(u >> 16);
}

__device__ __forceinline__ unsigned pkbf(float a, float b) {
    unsigned ua = __float_as_uint(a) + 0x8000u;
    unsigned ub = __float_as_uint(b) + 0x8000u;
    return __builtin_amdgcn_perm(ub, ua, 0x07060302u);  // [lo=bf(a), hi=bf(b)]
}

// ws layout (bytes) — unchanged:
//   W2T[t] @ t*32768          : [col2=128][k=128] bf16 k-contig      (98304)
//   W1T[t] @ 98304 + t*24576  : [hid=128][k=96]   bf16 k-contig      (73728)
//     header: k0=len(t0), k1=cos_t(t1), k2=sin_p(t2), k3=cos_p(t2),
//     k4=b1, k16+j = embedding row j
//   EB     @ 172032           : [aa=20][16] bf16                     (640)
__global__ __launch_bounds__(256)
void prep_kernel(const float* __restrict__ W1_0, const float* __restrict__ b1_0,
                 const float* __restrict__ W1_1, const float* __restrict__ b1_1,
                 const float* __restrict__ W1_2, const float* __restrict__ b1_2,
                 const float* __restrict__ W2_0, const float* __restrict__ W2_1,
                 const float* __restrict__ W2_2,
                 const float* __restrict__ emb, char* __restrict__ ws,
                 float* __restrict__ out)
{
    const int tid = blockIdx.x * 256 + threadIdx.x;
    const int np  = gridDim.x * 256;
    if (blockIdx.x == 0 && threadIdx.x < 128) out[threadIdx.x] = 0.0f;

    unsigned short* d2 = (unsigned short*)ws;
    for (int o = tid; o < 3 * 16384; o += np) {
        int t = o >> 14, r = o & 16383, col = r >> 7, k = r & 127;
        const float* W2 = (t == 0) ? W2_0 : (t == 1) ? W2_1 : W2_2;
        d2[o] = f2bf(W2[k * 128 + col]);
    }
    unsigned short* d1 = (unsigned short*)(ws + 98304);
    for (int o = tid; o < 3 * 12288; o += np) {
        int t = o / 12288, r = o - t * 12288, hid = r / 96, k = r - hid * 96;
        const int NE16 = (t == 0) ? 32 : (t == 1) ? 48 : 64;
        const int NG   = (t == 2) ? 2 : 1;
        const float* W1 = (t == 0) ? W1_0 : (t == 1) ? W1_1 : W1_2;
        const float* b1 = (t == 0) ? b1_0 : (t == 1) ? b1_1 : b1_2;
        float v = 0.0f;
        if (k >= 16) {
            int j = k - 16;
            if (j < NE16) v = W1[(NG + j) * 128 + hid];
        } else if (k == 4) v = b1[hid];
        else if (t == 0 && k == 0) v = W1_0[hid];
        else if (t == 1 && k == 1) v = W1_1[hid];
        else if (t == 2 && k == 2) v = W1_2[hid];
        else if (t == 2 && k == 3) v = W1_2[128 + hid];
        d1[o] = f2bf(v);
    }
    unsigned short* eb = (unsigned short*)(ws + 172032);
    for (int i = tid; i < 320; i += np) eb[i] = f2bf(emb[i]);
}

struct SMem {
    unsigned short H1d[2][64 * SHs]; // double-buffered 64-row H1 (2 x 17408 B)
    float  Rbuf[393];                // 131 rows x 3
    uint2  geomh[128];               // packed bf16 header per row
    int    seqb[132];
    unsigned short ebuf[320];        // [20][16] bf16
    float  part[4];
};

template<int TYPE>
__device__ __forceinline__ void load_a1(const char* __restrict__ ws,
                                        int wv, int ln31, int hi, FragU* A1)
{
    constexpr int STEPS = 1 + ((TYPE == 0) ? 2 : (TYPE == 1) ? 3 : 4);
    const unsigned short* w1t = (const unsigned short*)(ws + 98304 + TYPE * 24576);
#pragma unroll
    for (int s = 0; s < STEPS; ++s)
        A1[s].u = *(const uint4*)&w1t[(wv * 32 + ln31) * 96 + s * 16 + hi * 8];
}

template<int TYPE>
__device__ __forceinline__ void load_b2(const char* __restrict__ ws,
                                        const float* __restrict__ b2,
                                        const float* __restrict__ w3,
                                        int wv, int ln31, int hi,
                                        FragU* B2, float& b2v, float& w3v)
{
    const unsigned short* w2t = (const unsigned short*)(ws + TYPE * 32768);
#pragma unroll
    for (int s2 = 0; s2 < 8; ++s2)
        B2[s2].u = *(const uint4*)&w2t[(wv * 32 + ln31) * 128 + s2 * 16 + hi * 8];
    b2v = b2[wv * 32 + ln31];
    w3v = w3[wv * 32 + ln31];
}

// GEMM1 stage: rows [H*64, H*64+64) -> H1d[BUF]; A1 frags passed in.
template<int TYPE, int H, int BUF>
__device__ __forceinline__ void g1_run(SMem& sm, const FragU* A1,
                                       int wv, int ln31, int hi)
{
    constexpr int NEMB  = (TYPE == 0) ? 2 : (TYPE == 1) ? 3 : 4;
    constexpr int STEPS = 1 + NEMB;

    f32x16 acc1[2];
    acc1[0] = (f32x16)(0.f);
    acc1[1] = (f32x16)(0.f);

#pragma unroll
    for (int s = 0; s < STEPS; ++s)
#pragma unroll
        for (int rt = 0; rt < 2; ++rt) {
            const int row = H * 64 + rt * 32 + ln31;
            FragU bb;
            if (s == 0) {                      // header [len,cos_t,sin_p,cos_p,1,0..]
                if (hi == 0) {
                    uint2 g = sm.geomh[row];
                    bb.u = make_uint4(g.x, g.y, 0x00003F80u, 0u);
                } else {
                    bb.u = make_uint4(0u, 0u, 0u, 0u);
                }
            } else {                           // embedding row j = s-1
                bb.u = *(const uint4*)&sm.ebuf[sm.seqb[row + (s - 1)] * 16 + hi * 8];
            }
            acc1[rt] = __builtin_amdgcn_mfma_f32_32x32x16_bf16(A1[s].v, bb.v, acc1[rt], 0, 0, 0);
        }

    // H1 = relu -> H1d[BUF]; D: col=ln31 (row-local), hid = wv*32+8g+4hi+(reg&3)
#pragma unroll
    for (int rt = 0; rt < 2; ++rt) {
        const int rl = rt * 32 + ln31;
#pragma unroll
        for (int g = 0; g < 4; ++g) {
            float v0 = fmaxf(acc1[rt][4 * g + 0], 0.f);
            float v1 = fmaxf(acc1[rt][4 * g + 1], 0.f);
            float v2 = fmaxf(acc1[rt][4 * g + 2], 0.f);
            float v3 = fmaxf(acc1[rt][4 * g + 3], 0.f);
            uint2 pk;
            pk.x = pkbf(v0, v1);
            pk.y = pkbf(v2, v3);
            *(uint2*)&sm.H1d[BUF][rl * SHs + wv * 32 + 8 * g + 4 * hi] = pk;
        }
    }
}

// GEMM2 stage: H1d[BUF] x W2 -> dot into p4; B2 frags + b2v/w3v passed in.
template<int TYPE, int H, int BUF>
__device__ __forceinline__ void g2_run(SMem& sm, const FragU* B2,
                                       float b2v, float w3v,
                                       int i0, bool edge,
                                       int wv, int ln31, int hi, f32x4& p4)
{
    constexpr int ROWSB = Lc - 1 - TYPE;
    const f32x4 z4 = (f32x4){0.f, 0.f, 0.f, 0.f};

    f32x16 acc2[2];
    acc2[0] = (f32x16)(b2v);   // h2 + b2 straight out of the MFMA chain
    acc2[1] = (f32x16)(b2v);
#pragma unroll
    for (int s2 = 0; s2 < 8; ++s2)
#pragma unroll
        for (int rt = 0; rt < 2; ++rt) {
            bf16x8 aa = *(const bf16x8*)&sm.H1d[BUF][(rt * 32 + ln31) * SHs + s2 * 16 + hi * 8];
            acc2[rt] = __builtin_amdgcn_mfma_f32_32x32x16_bf16(aa, B2[s2].v, acc2[rt], 0, 0, 0);
        }

    f32x4 ls = z4;
    if (!edge) {               // interior block: no row checks at all
#pragma unroll
        for (int rt = 0; rt < 2; ++rt)
#pragma unroll
            for (int g = 0; g < 4; ++g) {
                f32x4 v;
                v[0] = acc2[rt][4 * g + 0]; v[1] = acc2[rt][4 * g + 1];
                v[2] = acc2[rt][4 * g + 2]; v[3] = acc2[rt][4 * g + 3];
                ls += __builtin_elementwise_max(v, z4);
            }
    } else {
#pragma unroll
        for (int rt = 0; rt < 2; ++rt)
#pragma unroll
            for (int g = 0; g < 4; ++g) {
                const int rbase = i0 + H * 64 + rt * 32 + 8 * g + 4 * hi;
#pragma unroll
                for (int rg = 0; rg < 4; ++rg)
                    if (rbase + rg < ROWSB)
                        ls[rg] += fmaxf(acc2[rt][4 * g + rg], 0.f);
            }
    }
    p4 += ls * w3v;
}

__global__ __launch_bounds__(256, 3)
void energy_kernel(const float* __restrict__ R, const int* __restrict__ seq,
                   const char* __restrict__ ws,
                   const float* b2_0, const float* b2_1, const float* b2_2,
                   const float* w3_0, const float* w3_1, const float* w3_2,
                   const float* b3_0, const float* b3_1, const float* b3_2,
                   float* __restrict__ out)
{
    __shared__ SMem sm;
    const int tid = threadIdx.x;
    const int b   = blockIdx.y;
    const int i0  = blockIdx.x * 128;
    const bool edge = (i0 + 131 > Lc);     // only the last block-column masks rows
    const int lane = tid & 63, wv = tid >> 6;
    const int ln31 = lane & 31, hi = lane >> 5;

    // ---- stage R / seq / ebuf (fast contiguous path off the tail column) ----
    if (!edge) {
        const float* Rb = &R[((size_t)b * Lc + i0) * 3];
        for (int t = tid; t < 393; t += 256) sm.Rbuf[t] = Rb[t];
        const int* sq = &seq[b * Lc + i0];
        for (int t = tid; t < 131; t += 256) sm.seqb[t] = sq[t];
    } else {
        for (int t = tid; t < 393; t += 256) {
            int lr = t / 3, comp = t - lr * 3;
            int row = min(i0 + lr, Lc - 1);
            sm.Rbuf[t] = R[((size_t)b * Lc + row) * 3 + comp];
        }
        for (int t = tid; t < 131; t += 256)
            sm.seqb[t] = seq[b * Lc + min(i0 + t, Lc - 1)];
    }
    {
        const uint4* se = (const uint4*)(ws + 172032);
        for (int t = tid; t < 40; t += 256) ((uint4*)sm.ebuf)[t] = se[t];
    }
    __syncthreads();

    // ---- geometry: each wave computes its own 32 rows -> packed header ----
    if (lane < 32) {
        const int r = wv * 32 + lane;
        const float* p0 = &sm.Rbuf[r * 3];
        float ax = p0[3] - p0[0], ay = p0[4] - p0[1], az = p0[5] - p0[2];
        float bx = p0[6] - p0[3], by = p0[7] - p0[4], bz = p0[8] - p0[5];
        float cx = p0[9] - p0[6], cy = p0[10] - p0[7], cz = p0[11] - p0[8];
        float na2 = ax * ax + ay * ay + az * az;
        float len = sqrtf(na2);
        float nb2 = bx * bx + by * by + bz * bz;
        float duv = -(ax * bx + ay * by + az * bz);
        float cost = fminf(fmaxf(duv / sqrtf(na2 * nb2), -1.0f), 1.0f);
        float n1x = ay * bz - az * by, n1y = az * bx - ax * bz, n1z = ax * by - ay * bx;
        float n2x = by * cz - bz * cy, n2y = bz * cx - bx * cz, n2z = bx * cy - by * cx;
        float binv = 1.0f / sqrtf(nb2);
        float ux = bx * binv, uy = by * binv, uz = bz * binv;
        float m1x = n1y * uz - n1z * uy, m1y = n1z * ux - n1x * uz, m1z = n1x * uy - n1y * ux;
        float yv = m1x * n2x + m1y * n2y + m1z * n2z;
        float xv = n1x * n2x + n1y * n2y + n1z * n2z;
        float inv = 1.0f / sqrtf(xv * xv + yv * yv);
        sm.geomh[r] = make_uint2(pkbf(len, cost), pkbf(yv * inv, xv * inv));
    }
    __syncthreads();

    // ---- pipelined stages with per-type hoisted frags (lazy loads) ----
    f32x4 p4 = (f32x4){0.f, 0.f, 0.f, 0.f};
    FragU A1[5], B2[8];
    float b2v, w3v;

    load_a1<0>(ws, wv, ln31, hi, A1);
    g1_run<0, 0, 0>(sm, A1, wv, ln31, hi);
    __syncthreads();
    load_b2<0>(ws, b2_0, w3_0, wv, ln31, hi, B2, b2v, w3v);
    g1_run<0, 1, 1>(sm, A1, wv, ln31, hi);
    g2_run<0, 0, 0>(sm, B2, b2v, w3v, i0, edge, wv, ln31, hi, p4);
    __syncthreads();
    load_a1<1>(ws, wv, ln31, hi, A1);
    g1_run<1, 0, 0>(sm, A1, wv, ln31, hi);
    g2_run<0, 1, 1>(sm, B2, b2v, w3v, i0, edge, wv, ln31, hi, p4);
    __syncthreads();
    load_b2<1>(ws, b2_1, w3_1, wv, ln31, hi, B2, b2v, w3v);
    g1_run<1, 1, 1>(sm, A1, wv, ln31, hi);
    g2_run<1, 0, 0>(sm, B2, b2v, w3v, i0, edge, wv, ln31, hi, p4);
    __syncthreads();
    load_a1<2>(ws, wv, ln31, hi, A1);
    g1_run<2, 0, 0>(sm, A1, wv, ln31, hi);
    g2_run<1, 1, 1>(sm, B2, b2v, w3v, i0, edge, wv, ln31, hi, p4);
    __syncthreads();
    load_b2<2>(ws, b2_2, w3_2, wv, ln31, hi, B2, b2v, w3v);
    g1_run<2, 1, 1>(sm, A1, wv, ln31, hi);
    g2_run<2, 0, 0>(sm, B2, b2v, w3v, i0, edge, wv, ln31, hi, p4);
    __syncthreads();
    g2_run<2, 1, 1>(sm, B2, b2v, w3v, i0, edge, wv, ln31, hi, p4);

    float p = p4[0] + p4[1] + p4[2] + p4[3];
#pragma unroll
    for (int off = 32; off > 0; off >>= 1)
        p += __shfl_down(p, off);
    if (lane == 0) sm.part[wv] = p;
    __syncthreads();
    if (tid == 0) {
        float tot = sm.part[0] + sm.part[1] + sm.part[2] + sm.part[3];
        tot += b3_0[0] * (float)min(Lc - 1 - i0, 128);
        tot += b3_1[0] * (float)min(Lc - 2 - i0, 128);
        tot += b3_2[0] * (float)min(Lc - 3 - i0, 128);
        atomicAdd(&out[b], tot);
    }
}

extern "C" void kernel_launch(void* const* d_in, const int* in_sizes, int n_in,
                              void* d_out, int out_size, void* d_ws, size_t ws_size,
                              hipStream_t stream) {
    const float* R   = (const float*)d_in[0];
    const int*   seq = (const int*)d_in[1];
    const float* emb = (const float*)d_in[2];
    float* out = (float*)d_out;
    char*  ws  = (char*)d_ws;

    prep_kernel<<<dim3(96), dim3(256), 0, stream>>>(
        (const float*)d_in[3],  (const float*)d_in[4],
        (const float*)d_in[9],  (const float*)d_in[10],
        (const float*)d_in[15], (const float*)d_in[16],
        (const float*)d_in[5],  (const float*)d_in[11], (const float*)d_in[17],
        emb, ws, out);

    dim3 grid(16, 128), block(256);
    energy_kernel<<<grid, block, 0, stream>>>(
        R, seq, ws,
        (const float*)d_in[6],  (const float*)d_in[12], (const float*)d_in[18],
        (const float*)d_in[7],  (const float*)d_in[13], (const float*)d_in[19],
        (const float*)d_in[8],  (const float*)d_in[14], (const float*)d_in[20],
        out);
}

// Round 16
// 156.986 us; speedup vs baseline: 1.0317x; 1.0317x over previous
//
#include <hip/hip_runtime.h>

// LocalEnergy R16 = R14 revert (best measured dispatch: 72.0 us).
// R12 pipeline + VALU diet: b2 folded into acc2 init, w3 applied once per
// stage, row-mask hoisted to a scalar edge branch, geometry spread across
// all 4 waves. R15's frag hoisting reverted (cost residency: 36%->25%).
// B=128, L=2048, E=16, H=128. Out = 128 f32.

typedef short bf16x8  __attribute__((ext_vector_type(8)));
typedef float f32x4   __attribute__((ext_vector_type(4)));
typedef float f32x16  __attribute__((ext_vector_type(16)));

constexpr int Lc  = 2048;
constexpr int SHs = 136;   // H1 row stride (shorts) = 272 B

union FragU { uint4 u; bf16x8 v; };

__device__ __forceinline__ unsigned short f2bf(float f) {
    union { float f; unsigned u; } v; v.f = f;
    unsigned u = v.u;
    u = u + 0x7FFFu + ((u >> 16) & 1u);   // RTNE
    return (unsigned short)(u >> 16);
}

__device__ __forceinline__ unsigned pkbf(float a, float b) {
    unsigned ua = __float_as_uint(a) + 0x8000u;
    unsigned ub = __float_as_uint(b) + 0x8000u;
    return __builtin_amdgcn_perm(ub, ua, 0x07060302u);  // [lo=bf(a), hi=bf(b)]
}

// ws layout (bytes):
//   W2T[t] @ t*32768          : [col2=128][k=128] bf16 k-contig      (98304)
//   W1T[t] @ 98304 + t*24576  : [hid=128][k=96]   bf16 k-contig      (73728)
//     header: k0=len(t0), k1=cos_t(t1), k2=sin_p(t2), k3=cos_p(t2),
//     k4=b1, k16+j = embedding row j
//   EB     @ 172032           : [aa=20][16] bf16                     (640)
__global__ __launch_bounds__(256)
void prep_kernel(const float* __restrict__ W1_0, const float* __restrict__ b1_0,
                 const float* __restrict__ W1_1, const float* __restrict__ b1_1,
                 const float* __restrict__ W1_2, const float* __restrict__ b1_2,
                 const float* __restrict__ W2_0, const float* __restrict__ W2_1,
                 const float* __restrict__ W2_2,
                 const float* __restrict__ emb, char* __restrict__ ws,
                 float* __restrict__ out)
{
    const int tid = blockIdx.x * 256 + threadIdx.x;
    const int np  = gridDim.x * 256;
    if (blockIdx.x == 0 && threadIdx.x < 128) out[threadIdx.x] = 0.0f;

    unsigned short* d2 = (unsigned short*)ws;
    for (int o = tid; o < 3 * 16384; o += np) {
        int t = o >> 14, r = o & 16383, col = r >> 7, k = r & 127;
        const float* W2 = (t == 0) ? W2_0 : (t == 1) ? W2_1 : W2_2;
        d2[o] = f2bf(W2[k * 128 + col]);
    }
    unsigned short* d1 = (unsigned short*)(ws + 98304);
    for (int o = tid; o < 3 * 12288; o += np) {
        int t = o / 12288, r = o - t * 12288, hid = r / 96, k = r - hid * 96;
        const int NE16 = (t == 0) ? 32 : (t == 1) ? 48 : 64;
        const int NG   = (t == 2) ? 2 : 1;
        const float* W1 = (t == 0) ? W1_0 : (t == 1) ? W1_1 : W1_2;
        const float* b1 = (t == 0) ? b1_0 : (t == 1) ? b1_1 : b1_2;
        float v = 0.0f;
        if (k >= 16) {
            int j = k - 16;
            if (j < NE16) v = W1[(NG + j) * 128 + hid];
        } else if (k == 4) v = b1[hid];
        else if (t == 0 && k == 0) v = W1_0[hid];
        else if (t == 1 && k == 1) v = W1_1[hid];
        else if (t == 2 && k == 2) v = W1_2[hid];
        else if (t == 2 && k == 3) v = W1_2[128 + hid];
        d1[o] = f2bf(v);
    }
    unsigned short* eb = (unsigned short*)(ws + 172032);
    for (int i = tid; i < 320; i += np) eb[i] = f2bf(emb[i]);
}

struct SMem {
    unsigned short H1d[2][64 * SHs]; // double-buffered 64-row H1 (2 x 17408 B)
    float  Rbuf[393];                // 131 rows x 3
    uint2  geomh[128];               // packed bf16 header per row
    int    seqb[132];
    unsigned short ebuf[320];        // [20][16] bf16
    float  part[4];
};

// GEMM1 stage: rows [H*64, H*64+64) -> H1d[BUF].
template<int TYPE, int H, int BUF>
__device__ __forceinline__ void g1_stage(SMem& sm, const char* __restrict__ ws,
                                         int wv, int ln31, int hi)
{
    constexpr int NEMB  = (TYPE == 0) ? 2 : (TYPE == 1) ? 3 : 4;
    constexpr int STEPS = 1 + NEMB;
    const unsigned short* w1t = (const unsigned short*)(ws + 98304 + TYPE * 24576);

    FragU A1[STEPS];
#pragma unroll
    for (int s = 0; s < STEPS; ++s)
        A1[s].u = *(const uint4*)&w1t[(wv * 32 + ln31) * 96 + s * 16 + hi * 8];

    f32x16 acc1[2];
    acc1[0] = (f32x16)(0.f);
    acc1[1] = (f32x16)(0.f);

#pragma unroll
    for (int s = 0; s < STEPS; ++s)
#pragma unroll
        for (int rt = 0; rt < 2; ++rt) {
            const int row = H * 64 + rt * 32 + ln31;
            FragU bb;
            if (s == 0) {                      // header [len,cos_t,sin_p,cos_p,1,0..]
                if (hi == 0) {
                    uint2 g = sm.geomh[row];
                    bb.u = make_uint4(g.x, g.y, 0x00003F80u, 0u);
                } else {
                    bb.u = make_uint4(0u, 0u, 0u, 0u);
                }
            } else {                           // embedding row j = s-1
                bb.u = *(const uint4*)&sm.ebuf[sm.seqb[row + (s - 1)] * 16 + hi * 8];
            }
            acc1[rt] = __builtin_amdgcn_mfma_f32_32x32x16_bf16(A1[s].v, bb.v, acc1[rt], 0, 0, 0);
        }

    // H1 = relu -> H1d[BUF]; D: col=ln31 (row-local), hid = wv*32+8g+4hi+(reg&3)
#pragma unroll
    for (int rt = 0; rt < 2; ++rt) {
        const int rl = rt * 32 + ln31;
#pragma unroll
        for (int g = 0; g < 4; ++g) {
            float v0 = fmaxf(acc1[rt][4 * g + 0], 0.f);
            float v1 = fmaxf(acc1[rt][4 * g + 1], 0.f);
            float v2 = fmaxf(acc1[rt][4 * g + 2], 0.f);
            float v3 = fmaxf(acc1[rt][4 * g + 3], 0.f);
            uint2 pk;
            pk.x = pkbf(v0, v1);
            pk.y = pkbf(v2, v3);
            *(uint2*)&sm.H1d[BUF][rl * SHs + wv * 32 + 8 * g + 4 * hi] = pk;
        }
    }
}

// GEMM2 stage: H1d[BUF] (64 rows) x W2 -> dot into p4. b2 folded in acc init;
// w3 applied once per stage; row-mask only on the edge block (scalar branch).
template<int TYPE, int H, int BUF>
__device__ __forceinline__ void g2_stage(SMem& sm, const char* __restrict__ ws,
                                         const float* __restrict__ b2,
                                         const float* __restrict__ w3,
                                         int i0, bool edge,
                                         int wv, int ln31, int hi, f32x4& p4)
{
    constexpr int ROWSB = Lc - 1 - TYPE;
    const unsigned short* w2t = (const unsigned short*)(ws + TYPE * 32768);
    const f32x4 z4 = (f32x4){0.f, 0.f, 0.f, 0.f};

    FragU B2[8];
#pragma unroll
    for (int s2 = 0; s2 < 8; ++s2)
        B2[s2].u = *(const uint4*)&w2t[(wv * 32 + ln31) * 128 + s2 * 16 + hi * 8];
    const float b2v = b2[wv * 32 + ln31];
    const float w3v = w3[wv * 32 + ln31];

    f32x16 acc2[2];
    acc2[0] = (f32x16)(b2v);   // h2 + b2 comes straight out of the MFMA chain
    acc2[1] = (f32x16)(b2v);
#pragma unroll
    for (int s2 = 0; s2 < 8; ++s2)
#pragma unroll
        for (int rt = 0; rt < 2; ++rt) {
            bf16x8 aa = *(const bf16x8*)&sm.H1d[BUF][(rt * 32 + ln31) * SHs + s2 * 16 + hi * 8];
            acc2[rt] = __builtin_amdgcn_mfma_f32_32x32x16_bf16(aa, B2[s2].v, acc2[rt], 0, 0, 0);
        }

    f32x4 ls = z4;
    if (!edge) {               // interior block: no row checks at all
#pragma unroll
        for (int rt = 0; rt < 2; ++rt)
#pragma unroll
            for (int g = 0; g < 4; ++g) {
                f32x4 v;
                v[0] = acc2[rt][4 * g + 0]; v[1] = acc2[rt][4 * g + 1];
                v[2] = acc2[rt][4 * g + 2]; v[3] = acc2[rt][4 * g + 3];
                ls += __builtin_elementwise_max(v, z4);
            }
    } else {
#pragma unroll
        for (int rt = 0; rt < 2; ++rt)
#pragma unroll
            for (int g = 0; g < 4; ++g) {
                const int rbase = i0 + H * 64 + rt * 32 + 8 * g + 4 * hi;
#pragma unroll
                for (int rg = 0; rg < 4; ++rg)
                    if (rbase + rg < ROWSB)
                        ls[rg] += fmaxf(acc2[rt][4 * g + rg], 0.f);
            }
    }
    p4 += ls * w3v;
}

__global__ __launch_bounds__(256, 4)
void energy_kernel(const float* __restrict__ R, const int* __restrict__ seq,
                   const char* __restrict__ ws,
                   const float* b2_0, const float* b2_1, const float* b2_2,
                   const float* w3_0, const float* w3_1, const float* w3_2,
                   const float* b3_0, const float* b3_1, const float* b3_2,
                   float* __restrict__ out)
{
    __shared__ SMem sm;
    const int tid = threadIdx.x;
    const int b   = blockIdx.y;
    const int i0  = blockIdx.x * 128;
    const bool edge = (i0 + 131 > Lc);     // only the last block-column masks rows
    const int lane = tid & 63, wv = tid >> 6;
    const int ln31 = lane & 31, hi = lane >> 5;

    // ---- stage R / seq / ebuf (fast contiguous path off the tail column) ----
    if (!edge) {
        const float* Rb = &R[((size_t)b * Lc + i0) * 3];
        for (int t = tid; t < 393; t += 256) sm.Rbuf[t] = Rb[t];
        const int* sq = &seq[b * Lc + i0];
        for (int t = tid; t < 131; t += 256) sm.seqb[t] = sq[t];
    } else {
        for (int t = tid; t < 393; t += 256) {
            int lr = t / 3, comp = t - lr * 3;
            int row = min(i0 + lr, Lc - 1);
            sm.Rbuf[t] = R[((size_t)b * Lc + row) * 3 + comp];
        }
        for (int t = tid; t < 131; t += 256)
            sm.seqb[t] = seq[b * Lc + min(i0 + t, Lc - 1)];
    }
    {
        const uint4* se = (const uint4*)(ws + 172032);
        for (int t = tid; t < 40; t += 256) ((uint4*)sm.ebuf)[t] = se[t];
    }
    __syncthreads();

    // ---- geometry: each wave computes its own 32 rows -> packed header ----
    if (lane < 32) {
        const int r = wv * 32 + lane;
        const float* p0 = &sm.Rbuf[r * 3];
        float ax = p0[3] - p0[0], ay = p0[4] - p0[1], az = p0[5] - p0[2];
        float bx = p0[6] - p0[3], by = p0[7] - p0[4], bz = p0[8] - p0[5];
        float cx = p0[9] - p0[6], cy = p0[10] - p0[7], cz = p0[11] - p0[8];
        float na2 = ax * ax + ay * ay + az * az;
        float len = sqrtf(na2);
        float nb2 = bx * bx + by * by + bz * bz;
        float duv = -(ax * bx + ay * by + az * bz);
        float cost = fminf(fmaxf(duv / sqrtf(na2 * nb2), -1.0f), 1.0f);
        float n1x = ay * bz - az * by, n1y = az * bx - ax * bz, n1z = ax * by - ay * bx;
        float n2x = by * cz - bz * cy, n2y = bz * cx - bx * cz, n2z = bx * cy - by * cx;
        float binv = 1.0f / sqrtf(nb2);
        float ux = bx * binv, uy = by * binv, uz = bz * binv;
        float m1x = n1y * uz - n1z * uy, m1y = n1z * ux - n1x * uz, m1z = n1x * uy - n1y * ux;
        float yv = m1x * n2x + m1y * n2y + m1z * n2z;
        float xv = n1x * n2x + n1y * n2y + n1z * n2z;
        float inv = 1.0f / sqrtf(xv * xv + yv * yv);
        sm.geomh[r] = make_uint2(pkbf(len, cost), pkbf(yv * inv, xv * inv));
    }
    __syncthreads();

    // ---- pipelined stages: G1(s+1) co-issued with G2(s), 1 barrier/stage ----
    f32x4 p4 = (f32x4){0.f, 0.f, 0.f, 0.f};

    g1_stage<0, 0, 0>(sm, ws, wv, ln31, hi);
    __syncthreads();
    g1_stage<0, 1, 1>(sm, ws, wv, ln31, hi);
    g2_stage<0, 0, 0>(sm, ws, b2_0, w3_0, i0, edge, wv, ln31, hi, p4);
    __syncthreads();
    g1_stage<1, 0, 0>(sm, ws, wv, ln31, hi);
    g2_stage<0, 1, 1>(sm, ws, b2_0, w3_0, i0, edge, wv, ln31, hi, p4);
    __syncthreads();
    g1_stage<1, 1, 1>(sm, ws, wv, ln31, hi);
    g2_stage<1, 0, 0>(sm, ws, b2_1, w3_1, i0, edge, wv, ln31, hi, p4);
    __syncthreads();
    g1_stage<2, 0, 0>(sm, ws, wv, ln31, hi);
    g2_stage<1, 1, 1>(sm, ws, b2_1, w3_1, i0, edge, wv, ln31, hi, p4);
    __syncthreads();
    g1_stage<2, 1, 1>(sm, ws, wv, ln31, hi);
    g2_stage<2, 0, 0>(sm, ws, b2_2, w3_2, i0, edge, wv, ln31, hi, p4);
    __syncthreads();
    g2_stage<2, 1, 1>(sm, ws, b2_2, w3_2, i0, edge, wv, ln31, hi, p4);

    float p = p4[0] + p4[1] + p4[2] + p4[3];
#pragma unroll
    for (int off = 32; off > 0; off >>= 1)
        p += __shfl_down(p, off);
    if (lane == 0) sm.part[wv] = p;
    __syncthreads();
    if (tid == 0) {
        float tot = sm.part[0] + sm.part[1] + sm.part[2] + sm.part[3];
        tot += b3_0[0] * (float)min(Lc - 1 - i0, 128);
        tot += b3_1[0] * (float)min(Lc - 2 - i0, 128);
        tot += b3_2[0] * (float)min(Lc - 3 - i0, 128);
        atomicAdd(&out[b], tot);
    }
}

extern "C" void kernel_launch(void* const* d_in, const int* in_sizes, int n_in,
                              void* d_out, int out_size, void* d_ws, size_t ws_size,
                              hipStream_t stream) {
    const float* R   = (const float*)d_in[0];
    const int*   seq = (const int*)d_in[1];
    const float* emb = (const float*)d_in[2];
    float* out = (float*)d_out;
    char*  ws  = (char*)d_ws;

    prep_kernel<<<dim3(96), dim3(256), 0, stream>>>(
        (const float*)d_in[3],  (const float*)d_in[4],
        (const float*)d_in[9],  (const float*)d_in[10],
        (const float*)d_in[15], (const float*)d_in[16],
        (const float*)d_in[5],  (const float*)d_in[11], (const float*)d_in[17],
        emb, ws, out);

    dim3 grid(16, 128), block(256);
    energy_kernel<<<grid, block, 0, stream>>>(
        R, seq, ws,
        (const float*)d_in[6],  (const float*)d_in[12], (const float*)d_in[18],
        (const float*)d_in[7],  (const float*)d_in[13], (const float*)d_in[19],
        (const float*)d_in[8],  (const float*)d_in[14], (const float*)d_in[20],
        out);
}